// Round 2
// baseline (157.825 us; speedup 1.0000x reference)
//
#include <hip/hip_runtime.h>
#include <stdint.h>

#define BATCH 4096
#define DDIM  768
#define EDIM  512
#define NSPLIT 16
#define LOG2E 1.44269504088896340736f

using short8  = __attribute__((ext_vector_type(8))) short;
using float4v = __attribute__((ext_vector_type(4))) float;

__device__ __forceinline__ unsigned short f2bf(float x) {
    union { float f; uint32_t u; } v; v.f = x;
    uint32_t u = v.u;
    u += 0x7FFFu + ((u >> 16) & 1u);   // round-to-nearest-even
    return (unsigned short)(u >> 16);
}
__device__ __forceinline__ float bf2f(unsigned short h) {
    union { uint32_t u; float f; } v; v.u = ((uint32_t)h) << 16;
    return v.f;
}

// async global->LDS, 16B per lane; LDS dst must be wave-uniform base + lane*16
__device__ __forceinline__ void gl2lds16(const void* g, void* l) {
    __builtin_amdgcn_global_load_lds(
        (const __attribute__((address_space(1))) void*)g,
        (__attribute__((address_space(3))) void*)l, 16, 0, 0);
}

// ---------------- fused: fp32->bf16 cvt (images,texts) + W transpose, one launch ----------------
// blocks [0,6144): cvt (3072 per tensor).  blocks [6144,6912): transpose (384 per tensor).
__global__ void prep(const float* __restrict__ images, const float* __restrict__ texts,
                     const float* __restrict__ W_img, const float* __restrict__ W_txt,
                     unsigned short* __restrict__ img_bf, unsigned short* __restrict__ txt_bf,
                     unsigned short* __restrict__ wt_img, unsigned short* __restrict__ wt_txt) {
    __shared__ float tile[32][33];
    int bid = blockIdx.x;
    if (bid < 6144) {
        int which = bid >= 3072;
        int i = (bid - (which ? 3072 : 0)) * 256 + threadIdx.x;
        const float* in = which ? texts : images;
        unsigned short* out = which ? txt_bf : img_bf;
        float4 v = ((const float4*)in)[i];
        ushort4 o;
        o.x = f2bf(v.x); o.y = f2bf(v.y); o.z = f2bf(v.z); o.w = f2bf(v.w);
        ((ushort4*)out)[i] = o;
        return;   // block-uniform early exit: no barrier on this path
    }
    int tb = bid - 6144;
    int which = tb >= 384;
    if (which) tb -= 384;
    const float* W = which ? W_txt : W_img;
    unsigned short* Wt = which ? wt_txt : wt_img;
    int n0 = (tb & 15) * 32, k0 = (tb >> 4) * 32;
    int tid = threadIdx.x;
    for (int p = 0; p < 4; ++p) {
        int e = tid + p * 256; int lr = e >> 5, lc = e & 31;
        tile[lc][lr] = W[(size_t)(k0 + lr) * EDIM + n0 + lc];
    }
    __syncthreads();
    for (int p = 0; p < 4; ++p) {
        int e = tid + p * 256; int lr = e >> 5, lc = e & 31;
        Wt[(size_t)(n0 + lr) * DDIM + k0 + lc] = f2bf(tile[lr][lc]);
    }
}

// ---------------- fused NT GEMM (both modalities): Cbf16[4096x512] = A @ W^T ----------------
// grid (32, 8, 2); block 256 = 4 waves; tile 128x64, wave = 32 rows x 64 cols.
// double-buffered LDS (48 KB), prefetch next K-step before MFMA, 1 barrier/K-step.
__global__ __launch_bounds__(256) void gemm_nt(const unsigned short* __restrict__ Aimg,
                                               const unsigned short* __restrict__ Atxt,
                                               const unsigned short* __restrict__ Bimg,
                                               const unsigned short* __restrict__ Btxt,
                                               unsigned short* __restrict__ Cimg,
                                               unsigned short* __restrict__ Ctxt) {
    const unsigned short* A  = blockIdx.z ? Atxt : Aimg;
    const unsigned short* Bm = blockIdx.z ? Btxt : Bimg;
    unsigned short* C        = blockIdx.z ? Ctxt : Cimg;
    __shared__ __align__(16) unsigned short As[2][128 * 64];  // 2 x 16 KB
    __shared__ __align__(16) unsigned short Bs[2][64 * 64];   // 2 x  8 KB
    int tid = threadIdx.x;
    int wave = tid >> 6, lane = tid & 63;
    int q = lane >> 4, r = lane & 15;
    int m0 = blockIdx.x * 128, n0 = blockIdx.y * 64;
    int sw = (r >> 1) & 3;

    const unsigned short* gsA[4];
    unsigned short* lsA[4];
    for (int i = 0; i < 4; ++i) {
        int u = i * 256 + tid;
        int kc2 = u >> 9, row = (u >> 2) & 127, kq = u & 3;
        int kq2 = kq ^ ((row >> 1) & 3);
        gsA[i] = &A[(size_t)(m0 + row) * DDIM + kc2 * 32 + kq2 * 8];
        lsA[i] = &As[0][u * 8];
    }
    const unsigned short* gsB[2];
    unsigned short* lsB[2];
    for (int i = 0; i < 2; ++i) {
        int u = i * 256 + tid;
        int kc2 = u >> 8, row = (u >> 2) & 63, kq = u & 3;
        int kq2 = kq ^ ((row >> 1) & 3);
        gsB[i] = &Bm[(size_t)(n0 + row) * DDIM + kc2 * 32 + kq2 * 8];
        lsB[i] = &Bs[0][u * 8];
    }

    float4v acc[2][4];
    for (int a = 0; a < 2; ++a)
        for (int t = 0; t < 4; ++t) acc[a][t] = (float4v){0.f, 0.f, 0.f, 0.f};

    for (int i = 0; i < 4; ++i) gl2lds16(gsA[i], lsA[i]);
    for (int i = 0; i < 2; ++i) gl2lds16(gsB[i], lsB[i]);
    __syncthreads();

    for (int it = 0; it < DDIM / 64; ++it) {
        int b = it & 1;
        if (it < DDIM / 64 - 1) {
            int k0 = (it + 1) * 64;
            for (int i = 0; i < 4; ++i) gl2lds16(gsA[i] + k0, lsA[i] + (b ^ 1) * (128 * 64));
            for (int i = 0; i < 2; ++i) gl2lds16(gsB[i] + k0, lsB[i] + (b ^ 1) * (64 * 64));
        }
        for (int kc2 = 0; kc2 < 2; ++kc2) {
            short8 a0 = *(const short8*)&As[b][kc2 * 4096 + (wave * 32 + r) * 32 + (q ^ sw) * 8];
            short8 a1 = *(const short8*)&As[b][kc2 * 4096 + (wave * 32 + 16 + r) * 32 + (q ^ sw) * 8];
            for (int t = 0; t < 4; ++t) {
                short8 bfr = *(const short8*)&Bs[b][kc2 * 2048 + (t * 16 + r) * 32 + (q ^ sw) * 8];
                acc[0][t] = __builtin_amdgcn_mfma_f32_16x16x32_bf16(a0, bfr, acc[0][t], 0, 0, 0);
                acc[1][t] = __builtin_amdgcn_mfma_f32_16x16x32_bf16(a1, bfr, acc[1][t], 0, 0, 0);
            }
        }
        __syncthreads();   // drains prefetch vmcnt + guards buffer reuse
    }
    for (int rg = 0; rg < 2; ++rg)
        for (int t = 0; t < 4; ++t)
            for (int g = 0; g < 4; ++g)
                C[(size_t)(m0 + wave * 32 + rg * 16 + q * 4 + g) * EDIM + n0 + t * 16 + r] =
                    f2bf(acc[rg][t][g]);
}

// ---------------- in-place row L2-normalize of bf16 projections (both) ----------------
__global__ void norm_rows(unsigned short* __restrict__ Pa, unsigned short* __restrict__ Pb) {
    unsigned short* P = blockIdx.y ? Pb : Pa;
    int wave = threadIdx.x >> 6, lane = threadIdx.x & 63;
    int row = blockIdx.x * 4 + wave;
    unsigned short* p = &P[(size_t)row * 512 + lane * 8];
    union { unsigned short us[8]; uint4 u4; } v;
    v.u4 = *(const uint4*)p;
    float f[8], s = 0.f;
    for (int j = 0; j < 8; ++j) { f[j] = bf2f(v.us[j]); s += f[j] * f[j]; }
    for (int off = 1; off < 64; off <<= 1) s += __shfl_xor(s, off);
    float rn = rsqrtf(s);
    for (int j = 0; j < 8; ++j) v.us[j] = f2bf(f[j] * rn);
    *(uint4*)p = v.u4;
}

// ---------------- raw dot: tvals[i] = dot(img_n[i], txt_n[labels[i]]) ----------------
__global__ void tdot(const unsigned short* __restrict__ img, const unsigned short* __restrict__ txt,
                     const int* __restrict__ labels, float* __restrict__ tout) {
    int wave = threadIdx.x >> 6, lane = threadIdx.x & 63;
    int row = blockIdx.x * 4 + wave;
    int lab = labels[row];
    union { unsigned short us[8]; uint4 u4; } a, b;
    a.u4 = *(const uint4*)&img[(size_t)row * 512 + lane * 8];
    b.u4 = *(const uint4*)&txt[(size_t)lab * 512 + lane * 8];
    float s = 0.f;
    for (int j = 0; j < 8; ++j) s += bf2f(a.us[j]) * bf2f(b.us[j]);
    for (int off = 1; off < 64; off <<= 1) s += __shfl_xor(s, off);
    if (lane == 0) tout[row] = s;
}

// ---------------- fused logits + fixed-max softmax sums + masked denom ----------------
// v3: block 256 = 4 waves; EACH WAVE OWNS 32 ROWS (two 16-row strips) -> every B-frag
// ds_read feeds TWO MFMAs (ratio 1:2 vs 1:1 before; LDS-read was the binding pipe).
// Grid (NSPLIT, 32) split-major: XCD = split%8, per-XCD txt working set 512 KB (L2-resident).
// A fragments af[2][16] register-resident (128 VGPR); __launch_bounds__(256,2) caps at 256.
// 8 stages of (64 cols x 256 k), double-buffered 2x32 KB LDS, prefetch-before-compute.
// Fixed max M = alpha (|logit| <= alpha, L2-normalized inputs) -> per-lane accumulation only.
__global__ __launch_bounds__(256, 2) void flash_pass(
    const unsigned short* __restrict__ img, const unsigned short* __restrict__ txt,
    const int* __restrict__ labels, const float* __restrict__ tvals,
    const float* __restrict__ ls,
    float* __restrict__ lP, float* __restrict__ dP) {
    __shared__ __align__(16) unsigned short Bs[2][16384];  // 2 x 32 KB
    int tid = threadIdx.x;
    int wave = tid >> 6, lane = tid & 63;
    int q = lane >> 4, r = lane & 15;
    int split = blockIdx.x;
    int row0 = blockIdx.y * 128 + wave * 32;
    float alpha = expf(ls[0]);
    float c1 = alpha * LOG2E;          // p = exp2(c1*(cos - 1)) = e^{s - M}

    // staging coords: 256 threads x 8 issues x 16B = 32 KB per stage
    // u = i*256+tid -> kc = i; row = (tid>>2)&63; kq = tid&3
    int srow = (tid >> 2) & 63, skp = tid & 3;
    int skp2 = skp ^ ((srow >> 1) & 3);
    int sw = (r >> 1) & 3;

    const unsigned short* gB0 = &txt[(size_t)(split * 256 + srow) * 512 + skp2 * 8];
    unsigned short* ld0 = &Bs[0][0] + (size_t)tid * 8;

    // issue stage 0 (ct=0,h=0) immediately so it flies under the af/labels loads
    for (int i = 0; i < 8; ++i) gl2lds16(gB0 + i * 32, ld0 + i * 2048);

    // A fragments (2 strips x 16 rows x K=512) register-resident: 128 VGPRs
    short8 af[2][16];
    for (int st = 0; st < 2; ++st)
        for (int kc = 0; kc < 16; ++kc)
            af[st][kc] = *(const short8*)&img[(size_t)(row0 + st * 16 + r) * 512 + kc * 32 + q * 8];

    int labr[2][4]; float tr[2][4];
    for (int st = 0; st < 2; ++st)
        for (int g = 0; g < 4; ++g) {
            int rw = row0 + st * 16 + q * 4 + g;
            labr[st][g] = labels[rw];
            tr[st][g] = tvals[rw];
        }
    float l[2][4] = {{0.f, 0.f, 0.f, 0.f}, {0.f, 0.f, 0.f, 0.f}};
    float d[2][4] = {{0.f, 0.f, 0.f, 0.f}, {0.f, 0.f, 0.f, 0.f}};
    float4v acc[2][4];
    for (int st = 0; st < 2; ++st)
        for (int t = 0; t < 4; ++t) acc[st][t] = (float4v){0.f, 0.f, 0.f, 0.f};

    __syncthreads();

    // stage s: ct = s>>1 (64-col tile), h = s&1 (256-k half), buf = s&1
    for (int s = 0; s < 8; ++s) {
        int buf = s & 1, h = s & 1;
        if (s < 7) {
            int sn = s + 1;
            const unsigned short* g = gB0 + (sn >> 1) * (64 * 512) + (sn & 1) * 256;
            unsigned short* ld = ld0 + (sn & 1) * 16384;
            for (int i = 0; i < 8; ++i) gl2lds16(g + i * 32, ld + i * 2048);
        }
        for (int kc = 0; kc < 8; ++kc) {
            short8 a0 = af[0][h * 8 + kc];
            short8 a1 = af[1][h * 8 + kc];
            for (int t = 0; t < 4; ++t) {
                short8 bfr = *(const short8*)&Bs[buf][(kc * 64 + t * 16 + r) * 32 + (q ^ sw) * 8];
                acc[0][t] = __builtin_amdgcn_mfma_f32_16x16x32_bf16(a0, bfr, acc[0][t], 0, 0, 0);
                acc[1][t] = __builtin_amdgcn_mfma_f32_16x16x32_bf16(a1, bfr, acc[1][t], 0, 0, 0);
            }
        }
        if (h == 1) {   // 64-col tile complete: fold into l/d, reset acc
            int colbase = split * 256 + (s >> 1) * 64;
            for (int t = 0; t < 4; ++t) {
                int lc = labels[colbase + t * 16 + r];
                for (int st = 0; st < 2; ++st)
                    for (int g = 0; g < 4; ++g) {
                        float a = acc[st][t][g];
                        float p = exp2f(fmaf(a, c1, -c1));
                        l[st][g] += p;
                        d[st][g] += ((a > tr[st][g]) && (lc != labr[st][g])) ? p : 0.f;
                    }
                for (int st = 0; st < 2; ++st) acc[st][t] = (float4v){0.f, 0.f, 0.f, 0.f};
            }
        }
        __syncthreads();   // drains prefetch vmcnt + guards buffer reuse
    }
    for (int st = 0; st < 2; ++st)
        for (int g = 0; g < 4; ++g) {
            float lv = l[st][g], dv = d[st][g];
            for (int off = 1; off < 16; off <<= 1) {
                lv += __shfl_xor(lv, off);
                dv += __shfl_xor(dv, off);
            }
            if (r == 0) {
                int rw = row0 + st * 16 + q * 4 + g;
                lP[(size_t)rw * NSPLIT + split] = lv;
                dP[(size_t)rw * NSPLIT + split] = dv;
            }
        }
}

// ---------------- merge splits + per-row losses + global sum (atomic) ----------------
__global__ void combine(const float* __restrict__ lP, const float* __restrict__ dP,
                        const float* __restrict__ tvals, const float* __restrict__ ls,
                        float* __restrict__ out) {
    int row = blockIdx.x * 256 + threadIdx.x;
    float alpha = expf(ls[0]);
    float L = 0.f, D = 0.f;
    for (int s = 0; s < NSPLIT; ++s) {
        L += lP[(size_t)row * NSPLIT + s];
        D += dP[(size_t)row * NSPLIT + s];
    }
    float tm = alpha * (tvals[row] - 1.0f);   // t - M, with M = alpha
    float clip = logf(L) - tm;
    float py = expf(tm) / L;
    float cmp = (D > 0.f) ? py / (D / L + 1e-10f) : 0.f;
    float v = clip + cmp;
    for (int off = 1; off < 64; off <<= 1) v += __shfl_xor(v, off);
    __shared__ float w4[4];
    int wave = threadIdx.x >> 6, lane = threadIdx.x & 63;
    if (lane == 0) w4[wave] = v;
    __syncthreads();
    if (threadIdx.x == 0)
        atomicAdd(out, (w4[0] + w4[1] + w4[2] + w4[3]) * (1.0f / BATCH));
}

extern "C" void kernel_launch(void* const* d_in, const int* in_sizes, int n_in,
                              void* d_out, int out_size, void* d_ws, size_t ws_size,
                              hipStream_t stream) {
    const float* images = (const float*)d_in[0];
    const float* texts  = (const float*)d_in[1];
    const int*   labels = (const int*)d_in[2];
    const float* W_img  = (const float*)d_in[3];
    const float* W_txt  = (const float*)d_in[4];
    const float* lscale = (const float*)d_in[5];
    float* out = (float*)d_out;

    char* ws = (char*)d_ws;
    unsigned short* img_bf = (unsigned short*)(ws + 0);           // 6,291,456 B
    unsigned short* txt_bf = (unsigned short*)(ws + 6291456);     // 6,291,456 B
    unsigned short* wt_img = (unsigned short*)(ws + 12582912);    //   786,432 B
    unsigned short* wt_txt = (unsigned short*)(ws + 13369344);    //   786,432 B
    unsigned short* proj_i = (unsigned short*)(ws + 14155776);    // 4,194,304 B (bf16 img_n)
    unsigned short* proj_t = (unsigned short*)(ws + 18350080);    // 4,194,304 B (bf16 txt_n)
    // aliased over dead img_bf region (written only after the fused gemm):
    float*          lP     = (float*)(ws + 0);                    //   262,144 B
    float*          dP     = (float*)(ws + 262144);               //   262,144 B
    float*          tvals  = (float*)(ws + 524288);               //    16,384 B

    hipMemsetAsync(out, 0, sizeof(float), stream);
    prep<<<6912, 256, 0, stream>>>(images, texts, W_img, W_txt, img_bf, txt_bf, wt_img, wt_txt);
    gemm_nt<<<dim3(BATCH / 128, EDIM / 64, 2), 256, 0, stream>>>(img_bf, txt_bf, wt_img, wt_txt,
                                                                 proj_i, proj_t);
    norm_rows<<<dim3(BATCH / 4, 2), 256, 0, stream>>>(proj_i, proj_t);
    tdot<<<BATCH / 4, 256, 0, stream>>>(proj_i, proj_t, labels, tvals);
    flash_pass<<<dim3(NSPLIT, BATCH / 128), 256, 0, stream>>>(proj_i, proj_t, labels, tvals,
                                                              lscale, lP, dP);
    combine<<<16, 256, 0, stream>>>(lP, dP, tvals, lscale, out);
}

// Round 3
// 140.986 us; speedup vs baseline: 1.1194x; 1.1194x over previous
//
#include <hip/hip_runtime.h>
#include <stdint.h>

#define BATCH 4096
#define DDIM  768
#define EDIM  512
#define NS    64          // column-split granularity of flash partials (4096/64)
#define LOG2E 1.44269504088896340736f

using short8  = __attribute__((ext_vector_type(8))) short;
using float4v = __attribute__((ext_vector_type(4))) float;

__device__ __forceinline__ unsigned short f2bf(float x) {
    union { float f; uint32_t u; } v; v.f = x;
    uint32_t u = v.u;
    u += 0x7FFFu + ((u >> 16) & 1u);   // round-to-nearest-even
    return (unsigned short)(u >> 16);
}
__device__ __forceinline__ float bf2f(unsigned short h) {
    union { uint32_t u; float f; } v; v.u = ((uint32_t)h) << 16;
    return v.f;
}

// async global->LDS, 16B per lane; LDS dst must be wave-uniform base + lane*16
__device__ __forceinline__ void gl2lds16(const void* g, void* l) {
    __builtin_amdgcn_global_load_lds(
        (const __attribute__((address_space(1))) void*)g,
        (__attribute__((address_space(3))) void*)l, 16, 0, 0);
}

// ---------------- fused: fp32->bf16 cvt (images,texts) + W transpose, one launch ----------------
__global__ void prep(const float* __restrict__ images, const float* __restrict__ texts,
                     const float* __restrict__ W_img, const float* __restrict__ W_txt,
                     unsigned short* __restrict__ img_bf, unsigned short* __restrict__ txt_bf,
                     unsigned short* __restrict__ wt_img, unsigned short* __restrict__ wt_txt) {
    __shared__ float tile[32][33];
    int bid = blockIdx.x;
    if (bid < 6144) {
        int which = bid >= 3072;
        int i = (bid - (which ? 3072 : 0)) * 256 + threadIdx.x;
        const float* in = which ? texts : images;
        unsigned short* out = which ? txt_bf : img_bf;
        float4 v = ((const float4*)in)[i];
        ushort4 o;
        o.x = f2bf(v.x); o.y = f2bf(v.y); o.z = f2bf(v.z); o.w = f2bf(v.w);
        ((ushort4*)out)[i] = o;
        return;   // block-uniform early exit: no barrier on this path
    }
    int tb = bid - 6144;
    int which = tb >= 384;
    if (which) tb -= 384;
    const float* W = which ? W_txt : W_img;
    unsigned short* Wt = which ? wt_txt : wt_img;
    int n0 = (tb & 15) * 32, k0 = (tb >> 4) * 32;
    int tid = threadIdx.x;
    for (int p = 0; p < 4; ++p) {
        int e = tid + p * 256; int lr = e >> 5, lc = e & 31;
        tile[lc][lr] = W[(size_t)(k0 + lr) * EDIM + n0 + lc];
    }
    __syncthreads();
    for (int p = 0; p < 4; ++p) {
        int e = tid + p * 256; int lr = e >> 5, lc = e & 31;
        Wt[(size_t)(n0 + lr) * DDIM + k0 + lc] = f2bf(tile[lr][lc]);
    }
}

// ---------------- fused NT GEMM (both modalities): Cbf16[4096x512] = A @ W^T ----------------
// grid (32, 8, 2); block 256 = 4 waves; tile 128x64, wave = 32 rows x 64 cols.
// double-buffered LDS (48 KB), prefetch next K-step before MFMA, 1 barrier/K-step.
__global__ __launch_bounds__(256) void gemm_nt(const unsigned short* __restrict__ Aimg,
                                               const unsigned short* __restrict__ Atxt,
                                               const unsigned short* __restrict__ Bimg,
                                               const unsigned short* __restrict__ Btxt,
                                               unsigned short* __restrict__ Cimg,
                                               unsigned short* __restrict__ Ctxt) {
    const unsigned short* A  = blockIdx.z ? Atxt : Aimg;
    const unsigned short* Bm = blockIdx.z ? Btxt : Bimg;
    unsigned short* C        = blockIdx.z ? Ctxt : Cimg;
    __shared__ __align__(16) unsigned short As[2][128 * 64];  // 2 x 16 KB
    __shared__ __align__(16) unsigned short Bs[2][64 * 64];   // 2 x  8 KB
    int tid = threadIdx.x;
    int wave = tid >> 6, lane = tid & 63;
    int q = lane >> 4, r = lane & 15;
    int m0 = blockIdx.x * 128, n0 = blockIdx.y * 64;
    int sw = (r >> 1) & 3;

    const unsigned short* gsA[4];
    unsigned short* lsA[4];
    for (int i = 0; i < 4; ++i) {
        int u = i * 256 + tid;
        int kc2 = u >> 9, row = (u >> 2) & 127, kq = u & 3;
        int kq2 = kq ^ ((row >> 1) & 3);
        gsA[i] = &A[(size_t)(m0 + row) * DDIM + kc2 * 32 + kq2 * 8];
        lsA[i] = &As[0][u * 8];
    }
    const unsigned short* gsB[2];
    unsigned short* lsB[2];
    for (int i = 0; i < 2; ++i) {
        int u = i * 256 + tid;
        int kc2 = u >> 8, row = (u >> 2) & 63, kq = u & 3;
        int kq2 = kq ^ ((row >> 1) & 3);
        gsB[i] = &Bm[(size_t)(n0 + row) * DDIM + kc2 * 32 + kq2 * 8];
        lsB[i] = &Bs[0][u * 8];
    }

    float4v acc[2][4];
    for (int a = 0; a < 2; ++a)
        for (int t = 0; t < 4; ++t) acc[a][t] = (float4v){0.f, 0.f, 0.f, 0.f};

    for (int i = 0; i < 4; ++i) gl2lds16(gsA[i], lsA[i]);
    for (int i = 0; i < 2; ++i) gl2lds16(gsB[i], lsB[i]);
    __syncthreads();

    for (int it = 0; it < DDIM / 64; ++it) {
        int b = it & 1;
        if (it < DDIM / 64 - 1) {
            int k0 = (it + 1) * 64;
            for (int i = 0; i < 4; ++i) gl2lds16(gsA[i] + k0, lsA[i] + (b ^ 1) * (128 * 64));
            for (int i = 0; i < 2; ++i) gl2lds16(gsB[i] + k0, lsB[i] + (b ^ 1) * (64 * 64));
        }
        for (int kc2 = 0; kc2 < 2; ++kc2) {
            short8 a0 = *(const short8*)&As[b][kc2 * 4096 + (wave * 32 + r) * 32 + (q ^ sw) * 8];
            short8 a1 = *(const short8*)&As[b][kc2 * 4096 + (wave * 32 + 16 + r) * 32 + (q ^ sw) * 8];
            for (int t = 0; t < 4; ++t) {
                short8 bfr = *(const short8*)&Bs[b][kc2 * 2048 + (t * 16 + r) * 32 + (q ^ sw) * 8];
                acc[0][t] = __builtin_amdgcn_mfma_f32_16x16x32_bf16(a0, bfr, acc[0][t], 0, 0, 0);
                acc[1][t] = __builtin_amdgcn_mfma_f32_16x16x32_bf16(a1, bfr, acc[1][t], 0, 0, 0);
            }
        }
        __syncthreads();   // drains prefetch vmcnt + guards buffer reuse
    }
    for (int rg = 0; rg < 2; ++rg)
        for (int t = 0; t < 4; ++t)
            for (int g = 0; g < 4; ++g)
                C[(size_t)(m0 + wave * 32 + rg * 16 + q * 4 + g) * EDIM + n0 + t * 16 + r] =
                    f2bf(acc[rg][t][g]);
}

// ---------------- in-place row L2-normalize of bf16 projections (both) ----------------
__global__ void norm_rows(unsigned short* __restrict__ Pa, unsigned short* __restrict__ Pb) {
    unsigned short* P = blockIdx.y ? Pb : Pa;
    int wave = threadIdx.x >> 6, lane = threadIdx.x & 63;
    int row = blockIdx.x * 4 + wave;
    unsigned short* p = &P[(size_t)row * 512 + lane * 8];
    union { unsigned short us[8]; uint4 u4; } v;
    v.u4 = *(const uint4*)p;
    float f[8], s = 0.f;
    for (int j = 0; j < 8; ++j) { f[j] = bf2f(v.us[j]); s += f[j] * f[j]; }
    for (int off = 1; off < 64; off <<= 1) s += __shfl_xor(s, off);
    float rn = rsqrtf(s);
    for (int j = 0; j < 8; ++j) v.us[j] = f2bf(f[j] * rn);
    *(uint4*)p = v.u4;
}

// ---------------- raw dot: tvals[i] = dot(img_n[i], txt_n[labels[i]]) ----------------
__global__ void tdot(const unsigned short* __restrict__ img, const unsigned short* __restrict__ txt,
                     const int* __restrict__ labels, float* __restrict__ tout) {
    int wave = threadIdx.x >> 6, lane = threadIdx.x & 63;
    int row = blockIdx.x * 4 + wave;
    int lab = labels[row];
    union { unsigned short us[8]; uint4 u4; } a, b;
    a.u4 = *(const uint4*)&img[(size_t)row * 512 + lane * 8];
    b.u4 = *(const uint4*)&txt[(size_t)lab * 512 + lane * 8];
    float s = 0.f;
    for (int j = 0; j < 8; ++j) s += bf2f(a.us[j]) * bf2f(b.us[j]);
    for (int off = 1; off < 64; off <<= 1) s += __shfl_xor(s, off);
    if (lane == 0) tout[row] = s;
}

// ---------------- fused logits + fixed-max softmax sums + masked denom ----------------
// v4: plain-GEMM block structure, fold fused as epilogue (legal because max is FIXED at
// M = alpha -> partial sums over columns commute; no online rescaling needed).
// Block 256 = 4 waves (2x2); tile 128 rows x 128 cols; FULL K=512 accumulated in regs.
// Wave = 64x64: per K=32 chunk 4 A + 4 B ds_read_b128 feed 16 MFMAs (ratio 0.5 vs 1.0).
// Both operands staged in LDS (reg file holds only acc[4][4] = 64 VGPR); labels/tvals
// loaded only in the epilogue; all reg arrays under #pragma unroll (no runtime indexing
// -> no scratch; R2's 72 MB spill traffic was exactly this failure).
// NO min-waves in launch_bounds: (256,2) empirically caps VGPR at 128 and spills.
// Grid (32 cols, 32 rows): XCD = colblock%8 -> per-XCD txt slice 512 KB, L2-resident.
__global__ __launch_bounds__(256) void flash_pass(
    const unsigned short* __restrict__ img, const unsigned short* __restrict__ txt,
    const int* __restrict__ labels, const float* __restrict__ tvals,
    const float* __restrict__ ls,
    float* __restrict__ lP, float* __restrict__ dP) {
    __shared__ __align__(16) unsigned short As[2][128 * 64];  // 2 x 16 KB
    __shared__ __align__(16) unsigned short Bs[2][128 * 64];  // 2 x 16 KB
    int tid = threadIdx.x;
    int wave = tid >> 6, lane = tid & 63;
    int wr = wave >> 1, wc = wave & 1;
    int q = lane >> 4, r = lane & 15;
    int n0 = blockIdx.x * 128;   // col block (fast dim -> XCD locality of txt panels)
    int m0 = blockIdx.y * 128;   // row block
    float alpha = expf(ls[0]);
    float c1 = alpha * LOG2E;    // p = exp2(c1*(cos - 1)) = e^{s - M}, M = alpha
    int sw = (r >> 1) & 3;

    // staging: per K=64 step, A tile 128x64 (16 KB, 4 issues) + B tile 128x64 (4 issues)
    const unsigned short* gsA[4]; const unsigned short* gsB[4];
    unsigned short *lsA[4], *lsB[4];
    for (int i = 0; i < 4; ++i) {
        int u = i * 256 + tid;
        int kc2 = u >> 9, row = (u >> 2) & 127, kq = u & 3;
        int kq2 = kq ^ ((row >> 1) & 3);   // XOR bank swizzle (verified conflict-free)
        gsA[i] = &img[(size_t)(m0 + row) * 512 + kc2 * 32 + kq2 * 8];
        gsB[i] = &txt[(size_t)(n0 + row) * 512 + kc2 * 32 + kq2 * 8];
        lsA[i] = &As[0][u * 8];
        lsB[i] = &Bs[0][u * 8];
    }

    float4v acc[4][4];
    #pragma unroll
    for (int st = 0; st < 4; ++st)
        #pragma unroll
        for (int cf = 0; cf < 4; ++cf) acc[st][cf] = (float4v){0.f, 0.f, 0.f, 0.f};

    for (int i = 0; i < 4; ++i) gl2lds16(gsA[i], lsA[i]);
    for (int i = 0; i < 4; ++i) gl2lds16(gsB[i], lsB[i]);
    __syncthreads();

    for (int it = 0; it < 8; ++it) {
        int b = it & 1;
        if (it < 7) {
            int k0 = (it + 1) * 64;
            for (int i = 0; i < 4; ++i) gl2lds16(gsA[i] + k0, lsA[i] + (b ^ 1) * (128 * 64));
            for (int i = 0; i < 4; ++i) gl2lds16(gsB[i] + k0, lsB[i] + (b ^ 1) * (128 * 64));
        }
        #pragma unroll
        for (int kc2 = 0; kc2 < 2; ++kc2) {
            short8 av[4], bv[4];
            #pragma unroll
            for (int st = 0; st < 4; ++st)
                av[st] = *(const short8*)&As[b][kc2 * 4096 + (wr * 64 + st * 16 + r) * 32 + (q ^ sw) * 8];
            #pragma unroll
            for (int cf = 0; cf < 4; ++cf)
                bv[cf] = *(const short8*)&Bs[b][kc2 * 4096 + (wc * 64 + cf * 16 + r) * 32 + (q ^ sw) * 8];
            #pragma unroll
            for (int st = 0; st < 4; ++st)
                #pragma unroll
                for (int cf = 0; cf < 4; ++cf)
                    acc[st][cf] = __builtin_amdgcn_mfma_f32_16x16x32_bf16(av[st], bv[cf],
                                                                          acc[st][cf], 0, 0, 0);
        }
        __syncthreads();   // drains prefetch vmcnt + guards buffer reuse
    }

    // epilogue: exp + masked sums, then 16-lane reduce, one partial per (row, 64-col panel)
    int lc[4];
    #pragma unroll
    for (int cf = 0; cf < 4; ++cf) lc[cf] = labels[n0 + wc * 64 + cf * 16 + r];
    int cb = blockIdx.x * 2 + wc;
    #pragma unroll
    for (int st = 0; st < 4; ++st) {
        int labr[4]; float tr[4];
        #pragma unroll
        for (int g = 0; g < 4; ++g) {
            int rw = m0 + wr * 64 + st * 16 + q * 4 + g;
            labr[g] = labels[rw];
            tr[g] = tvals[rw];
        }
        float l4[4] = {0.f, 0.f, 0.f, 0.f}, d4[4] = {0.f, 0.f, 0.f, 0.f};
        #pragma unroll
        for (int cf = 0; cf < 4; ++cf)
            #pragma unroll
            for (int g = 0; g < 4; ++g) {
                float a = acc[st][cf][g];
                float p = exp2f(fmaf(a, c1, -c1));
                l4[g] += p;
                d4[g] += ((a > tr[g]) && (lc[cf] != labr[g])) ? p : 0.f;
            }
        #pragma unroll
        for (int g = 0; g < 4; ++g) {
            float lv = l4[g], dv = d4[g];
            for (int off = 1; off < 16; off <<= 1) {
                lv += __shfl_xor(lv, off);
                dv += __shfl_xor(dv, off);
            }
            if (r == 0) {
                int rw = m0 + wr * 64 + st * 16 + q * 4 + g;
                lP[(size_t)rw * NS + cb] = lv;
                dP[(size_t)rw * NS + cb] = dv;
            }
        }
    }
}

// ---------------- merge partials + per-row losses + global sum (atomic) ----------------
__global__ void combine(const float* __restrict__ lP, const float* __restrict__ dP,
                        const float* __restrict__ tvals, const float* __restrict__ ls,
                        float* __restrict__ out) {
    int row = blockIdx.x * 256 + threadIdx.x;
    float alpha = expf(ls[0]);
    float L = 0.f, D = 0.f;
    for (int s = 0; s < NS; ++s) {
        L += lP[(size_t)row * NS + s];
        D += dP[(size_t)row * NS + s];
    }
    float tm = alpha * (tvals[row] - 1.0f);   // t - M, with M = alpha
    float clip = logf(L) - tm;
    float py = expf(tm) / L;
    float cmp = (D > 0.f) ? py / (D / L + 1e-10f) : 0.f;
    float v = clip + cmp;
    for (int off = 1; off < 64; off <<= 1) v += __shfl_xor(v, off);
    __shared__ float w4[4];
    int wave = threadIdx.x >> 6, lane = threadIdx.x & 63;
    if (lane == 0) w4[wave] = v;
    __syncthreads();
    if (threadIdx.x == 0)
        atomicAdd(out, (w4[0] + w4[1] + w4[2] + w4[3]) * (1.0f / BATCH));
}

extern "C" void kernel_launch(void* const* d_in, const int* in_sizes, int n_in,
                              void* d_out, int out_size, void* d_ws, size_t ws_size,
                              hipStream_t stream) {
    const float* images = (const float*)d_in[0];
    const float* texts  = (const float*)d_in[1];
    const int*   labels = (const int*)d_in[2];
    const float* W_img  = (const float*)d_in[3];
    const float* W_txt  = (const float*)d_in[4];
    const float* lscale = (const float*)d_in[5];
    float* out = (float*)d_out;

    char* ws = (char*)d_ws;
    unsigned short* img_bf = (unsigned short*)(ws + 0);           // 6,291,456 B
    unsigned short* txt_bf = (unsigned short*)(ws + 6291456);     // 6,291,456 B
    unsigned short* wt_img = (unsigned short*)(ws + 12582912);    //   786,432 B
    unsigned short* wt_txt = (unsigned short*)(ws + 13369344);    //   786,432 B
    unsigned short* proj_i = (unsigned short*)(ws + 14155776);    // 4,194,304 B (bf16 img_n)
    unsigned short* proj_t = (unsigned short*)(ws + 18350080);    // 4,194,304 B (bf16 txt_n)
    // aliased over dead img_bf region (written only after the fused gemm):
    float*          lP     = (float*)(ws + 0);                    // 1,048,576 B [4096][NS]
    float*          dP     = (float*)(ws + 1048576);              // 1,048,576 B
    float*          tvals  = (float*)(ws + 2097152);              //    16,384 B

    hipMemsetAsync(out, 0, sizeof(float), stream);
    prep<<<6912, 256, 0, stream>>>(images, texts, W_img, W_txt, img_bf, txt_bf, wt_img, wt_txt);
    gemm_nt<<<dim3(BATCH / 128, EDIM / 64, 2), 256, 0, stream>>>(img_bf, txt_bf, wt_img, wt_txt,
                                                                 proj_i, proj_t);
    norm_rows<<<dim3(BATCH / 4, 2), 256, 0, stream>>>(proj_i, proj_t);
    tdot<<<BATCH / 4, 256, 0, stream>>>(proj_i, proj_t, labels, tvals);
    flash_pass<<<dim3(BATCH / 128, BATCH / 128), 256, 0, stream>>>(proj_i, proj_t, labels, tvals,
                                                                   lscale, lP, dP);
    combine<<<16, 256, 0, stream>>>(lP, dP, tvals, lscale, out);
}

// Round 4
// 139.503 us; speedup vs baseline: 1.1313x; 1.0106x over previous
//
#include <hip/hip_runtime.h>
#include <stdint.h>

#define BATCH 4096
#define DDIM  768
#define EDIM  512
#define NS    64          // column-split granularity of flash partials (4096/64)
#define LOG2E 1.44269504088896340736f

using short8  = __attribute__((ext_vector_type(8))) short;
using float4v = __attribute__((ext_vector_type(4))) float;

__device__ __forceinline__ unsigned short f2bf(float x) {
    union { float f; uint32_t u; } v; v.f = x;
    uint32_t u = v.u;
    u += 0x7FFFu + ((u >> 16) & 1u);   // round-to-nearest-even
    return (unsigned short)(u >> 16);
}
__device__ __forceinline__ float bf2f(unsigned short h) {
    union { uint32_t u; float f; } v; v.u = ((uint32_t)h) << 16;
    return v.f;
}

// async global->LDS, 16B per lane; LDS dst must be wave-uniform base + lane*16
__device__ __forceinline__ void gl2lds16(const void* g, void* l) {
    __builtin_amdgcn_global_load_lds(
        (const __attribute__((address_space(1))) void*)g,
        (__attribute__((address_space(3))) void*)l, 16, 0, 0);
}

// ---------------- fused: fp32->bf16 cvt (images,texts) + W transpose, one launch ----------------
__global__ void prep(const float* __restrict__ images, const float* __restrict__ texts,
                     const float* __restrict__ W_img, const float* __restrict__ W_txt,
                     unsigned short* __restrict__ img_bf, unsigned short* __restrict__ txt_bf,
                     unsigned short* __restrict__ wt_img, unsigned short* __restrict__ wt_txt) {
    __shared__ float tile[32][33];
    int bid = blockIdx.x;
    if (bid < 6144) {
        int which = bid >= 3072;
        int i = (bid - (which ? 3072 : 0)) * 256 + threadIdx.x;
        const float* in = which ? texts : images;
        unsigned short* out = which ? txt_bf : img_bf;
        float4 v = ((const float4*)in)[i];
        ushort4 o;
        o.x = f2bf(v.x); o.y = f2bf(v.y); o.z = f2bf(v.z); o.w = f2bf(v.w);
        ((ushort4*)out)[i] = o;
        return;   // block-uniform early exit: no barrier on this path
    }
    int tb = bid - 6144;
    int which = tb >= 384;
    if (which) tb -= 384;
    const float* W = which ? W_txt : W_img;
    unsigned short* Wt = which ? wt_txt : wt_img;
    int n0 = (tb & 15) * 32, k0 = (tb >> 4) * 32;
    int tid = threadIdx.x;
    for (int p = 0; p < 4; ++p) {
        int e = tid + p * 256; int lr = e >> 5, lc = e & 31;
        tile[lc][lr] = W[(size_t)(k0 + lr) * EDIM + n0 + lc];
    }
    __syncthreads();
    for (int p = 0; p < 4; ++p) {
        int e = tid + p * 256; int lr = e >> 5, lc = e & 31;
        Wt[(size_t)(n0 + lr) * DDIM + k0 + lc] = f2bf(tile[lr][lc]);
    }
}

// ---------------- fused NT GEMM (both modalities): Cbf16[4096x512] = A @ W^T ----------------
// grid (32, 8, 2); block 256 = 4 waves; tile 128x64, wave = 32 rows x 64 cols.
// double-buffered LDS (48 KB), prefetch next K-step before MFMA, 1 barrier/K-step.
__global__ __launch_bounds__(256) void gemm_nt(const unsigned short* __restrict__ Aimg,
                                               const unsigned short* __restrict__ Atxt,
                                               const unsigned short* __restrict__ Bimg,
                                               const unsigned short* __restrict__ Btxt,
                                               unsigned short* __restrict__ Cimg,
                                               unsigned short* __restrict__ Ctxt) {
    const unsigned short* A  = blockIdx.z ? Atxt : Aimg;
    const unsigned short* Bm = blockIdx.z ? Btxt : Bimg;
    unsigned short* C        = blockIdx.z ? Ctxt : Cimg;
    __shared__ __align__(16) unsigned short As[2][128 * 64];  // 2 x 16 KB
    __shared__ __align__(16) unsigned short Bs[2][64 * 64];   // 2 x  8 KB
    int tid = threadIdx.x;
    int wave = tid >> 6, lane = tid & 63;
    int q = lane >> 4, r = lane & 15;
    int m0 = blockIdx.x * 128, n0 = blockIdx.y * 64;
    int sw = (r >> 1) & 3;

    const unsigned short* gsA[4];
    unsigned short* lsA[4];
    for (int i = 0; i < 4; ++i) {
        int u = i * 256 + tid;
        int kc2 = u >> 9, row = (u >> 2) & 127, kq = u & 3;
        int kq2 = kq ^ ((row >> 1) & 3);
        gsA[i] = &A[(size_t)(m0 + row) * DDIM + kc2 * 32 + kq2 * 8];
        lsA[i] = &As[0][u * 8];
    }
    const unsigned short* gsB[2];
    unsigned short* lsB[2];
    for (int i = 0; i < 2; ++i) {
        int u = i * 256 + tid;
        int kc2 = u >> 8, row = (u >> 2) & 63, kq = u & 3;
        int kq2 = kq ^ ((row >> 1) & 3);
        gsB[i] = &Bm[(size_t)(n0 + row) * DDIM + kc2 * 32 + kq2 * 8];
        lsB[i] = &Bs[0][u * 8];
    }

    float4v acc[2][4];
    for (int a = 0; a < 2; ++a)
        for (int t = 0; t < 4; ++t) acc[a][t] = (float4v){0.f, 0.f, 0.f, 0.f};

    for (int i = 0; i < 4; ++i) gl2lds16(gsA[i], lsA[i]);
    for (int i = 0; i < 2; ++i) gl2lds16(gsB[i], lsB[i]);
    __syncthreads();

    for (int it = 0; it < DDIM / 64; ++it) {
        int b = it & 1;
        if (it < DDIM / 64 - 1) {
            int k0 = (it + 1) * 64;
            for (int i = 0; i < 4; ++i) gl2lds16(gsA[i] + k0, lsA[i] + (b ^ 1) * (128 * 64));
            for (int i = 0; i < 2; ++i) gl2lds16(gsB[i] + k0, lsB[i] + (b ^ 1) * (64 * 64));
        }
        for (int kc2 = 0; kc2 < 2; ++kc2) {
            short8 a0 = *(const short8*)&As[b][kc2 * 4096 + (wave * 32 + r) * 32 + (q ^ sw) * 8];
            short8 a1 = *(const short8*)&As[b][kc2 * 4096 + (wave * 32 + 16 + r) * 32 + (q ^ sw) * 8];
            for (int t = 0; t < 4; ++t) {
                short8 bfr = *(const short8*)&Bs[b][kc2 * 2048 + (t * 16 + r) * 32 + (q ^ sw) * 8];
                acc[0][t] = __builtin_amdgcn_mfma_f32_16x16x32_bf16(a0, bfr, acc[0][t], 0, 0, 0);
                acc[1][t] = __builtin_amdgcn_mfma_f32_16x16x32_bf16(a1, bfr, acc[1][t], 0, 0, 0);
            }
        }
        __syncthreads();   // drains prefetch vmcnt + guards buffer reuse
    }
    for (int rg = 0; rg < 2; ++rg)
        for (int t = 0; t < 4; ++t)
            for (int g = 0; g < 4; ++g)
                C[(size_t)(m0 + wave * 32 + rg * 16 + q * 4 + g) * EDIM + n0 + t * 16 + r] =
                    f2bf(acc[rg][t][g]);
}

// ---------------- in-place row L2-normalize of bf16 projections (both) ----------------
__global__ void norm_rows(unsigned short* __restrict__ Pa, unsigned short* __restrict__ Pb) {
    unsigned short* P = blockIdx.y ? Pb : Pa;
    int wave = threadIdx.x >> 6, lane = threadIdx.x & 63;
    int row = blockIdx.x * 4 + wave;
    unsigned short* p = &P[(size_t)row * 512 + lane * 8];
    union { unsigned short us[8]; uint4 u4; } v;
    v.u4 = *(const uint4*)p;
    float f[8], s = 0.f;
    for (int j = 0; j < 8; ++j) { f[j] = bf2f(v.us[j]); s += f[j] * f[j]; }
    for (int off = 1; off < 64; off <<= 1) s += __shfl_xor(s, off);
    float rn = rsqrtf(s);
    for (int j = 0; j < 8; ++j) v.us[j] = f2bf(f[j] * rn);
    *(uint4*)p = v.u4;
}

// ---------------- raw dot: tvals[i] = dot(img_n[i], txt_n[labels[i]]) ----------------
__global__ void tdot(const unsigned short* __restrict__ img, const unsigned short* __restrict__ txt,
                     const int* __restrict__ labels, float* __restrict__ tout) {
    int wave = threadIdx.x >> 6, lane = threadIdx.x & 63;
    int row = blockIdx.x * 4 + wave;
    int lab = labels[row];
    union { unsigned short us[8]; uint4 u4; } a, b;
    a.u4 = *(const uint4*)&img[(size_t)row * 512 + lane * 8];
    b.u4 = *(const uint4*)&txt[(size_t)lab * 512 + lane * 8];
    float s = 0.f;
    for (int j = 0; j < 8; ++j) s += bf2f(a.us[j]) * bf2f(b.us[j]);
    for (int off = 1; off < 64; off <<= 1) s += __shfl_xor(s, off);
    if (lane == 0) tout[row] = s;
}

// ---------------- fused logits + fixed-max softmax sums + masked denom ----------------
// v5: m201-style 8-phase-class schedule. BM=BN=256, BK=64, 512 thr = 8 waves (2Mx4N),
// wave tile 128x64, acc[8][4] (128 VGPR). LDS 2x32+2x32 = 128 KB double-buffered.
// Per K-tile: 4 phases {ds_read subtile -> 2x gl2lds prefetch -> sched_barrier ->
// s_barrier -> setprio(1) -> 16 MFMA -> setprio(0) -> s_barrier}; vmcnt(0) only at the
// tile boundary (loads were issued 3-4 phases earlier => effectively counted).
// 2-phase structures measured ~430-600 TF here (R0-R3); this schedule targets >1 PF.
// Fold fused as epilogue (fixed max M = alpha -> column partial sums commute).
// Grid (16,16) = 256 blocks = 1/CU. No min-waves in launch_bounds (R2 spill lesson).
__global__ __launch_bounds__(512) void flash_pass(
    const unsigned short* __restrict__ img, const unsigned short* __restrict__ txt,
    const int* __restrict__ labels, const float* __restrict__ tvals,
    const float* __restrict__ ls,
    float* __restrict__ lP, float* __restrict__ dP) {
    __shared__ __align__(16) unsigned short As[2][16384];  // 2 x 32 KB: [kc2][256 rows][32]
    __shared__ __align__(16) unsigned short Bs[2][16384];  // 2 x 32 KB
    int tid = threadIdx.x;
    int wave = tid >> 6, lane = tid & 63;
    int wr = wave >> 2, wc = wave & 3;     // 2 row-halves x 4 col-quarters
    int q = lane >> 4, r = lane & 15;
    int n0 = blockIdx.x * 256;   // col block
    int m0 = blockIdx.y * 256;   // row block
    float alpha = expf(ls[0]);
    float c1 = alpha * LOG2E;    // p = exp2(c1*(cos - 1)) = e^{s - M}, M = alpha
    int sw = (r >> 1) & 3;

    // staging geometry (identical for A and B): K-tile = 256 rows x 64 k = 32 KB
    // granule u = i*512 + tid (i=0..3): kc2 = u>>10, row = (u>>2)&255, kq = u&3
    int soff[4], slds[4];
    for (int i = 0; i < 4; ++i) {
        int u = i * 512 + tid;
        int kc2 = u >> 10, row = (u >> 2) & 255, kq = u & 3;
        int kq2 = kq ^ ((row >> 1) & 3);   // 16B-granule XOR swizzle (conflict-free, R2-verified)
        soff[i] = row * 512 + kc2 * 32 + kq2 * 8;
        slds[i] = u * 8;
    }
    const unsigned short* gA = img + (size_t)m0 * 512;
    const unsigned short* gB = txt + (size_t)n0 * 512;

    float4v acc[8][4];
    #pragma unroll
    for (int s = 0; s < 8; ++s)
        #pragma unroll
        for (int c = 0; c < 4; ++c) acc[s][c] = (float4v){0.f, 0.f, 0.f, 0.f};

    // prologue: stage K-tile 0 into buf 0
    #pragma unroll
    for (int i = 0; i < 4; ++i) gl2lds16(gA + soff[i], &As[0][slds[i]]);
    #pragma unroll
    for (int i = 0; i < 4; ++i) gl2lds16(gB + soff[i], &Bs[0][slds[i]]);
    asm volatile("s_waitcnt vmcnt(0)" ::: "memory");
    __builtin_amdgcn_s_barrier();

    short8 av[4][2];        // current row-half: 4 st-frags x 2 kc2
    short8 bv[2][2][2];     // [n2][j][kc2]: col frags cf = n2*2+j

    for (int kt = 0; kt < 8; ++kt) {
        const unsigned short* As_ = &As[kt & 1][0];
        const unsigned short* Bs_ = &Bs[kt & 1][0];
        unsigned short* Asn = &As[(kt & 1) ^ 1][0];
        unsigned short* Bsn = &Bs[(kt & 1) ^ 1][0];
        int kn = (kt + 1) * 64;
        bool pf = kt < 7;

        // ---- P1: read av(h=0) + bv(n2=0); stage A issues 0,1 ----
        #pragma unroll
        for (int s = 0; s < 4; ++s)
            #pragma unroll
            for (int k = 0; k < 2; ++k)
                av[s][k] = *(const short8*)&As_[k * 8192 + (wr * 128 + s * 16 + r) * 32 + (q ^ sw) * 8];
        #pragma unroll
        for (int j = 0; j < 2; ++j)
            #pragma unroll
            for (int k = 0; k < 2; ++k)
                bv[0][j][k] = *(const short8*)&Bs_[k * 8192 + (wc * 64 + j * 16 + r) * 32 + (q ^ sw) * 8];
        if (pf) { gl2lds16(gA + kn + soff[0], Asn + slds[0]);
                  gl2lds16(gA + kn + soff[1], Asn + slds[1]); }
        __builtin_amdgcn_sched_barrier(0);
        __builtin_amdgcn_s_barrier();
        __builtin_amdgcn_s_setprio(1);
        #pragma unroll
        for (int s = 0; s < 4; ++s)
            #pragma unroll
            for (int j = 0; j < 2; ++j)
                #pragma unroll
                for (int k = 0; k < 2; ++k)
                    acc[s][j] = __builtin_amdgcn_mfma_f32_16x16x32_bf16(av[s][k], bv[0][j][k],
                                                                        acc[s][j], 0, 0, 0);
        __builtin_amdgcn_s_setprio(0);
        __builtin_amdgcn_s_barrier();

        // ---- P2: read bv(n2=1); stage A issues 2,3 ----
        #pragma unroll
        for (int j = 0; j < 2; ++j)
            #pragma unroll
            for (int k = 0; k < 2; ++k)
                bv[1][j][k] = *(const short8*)&Bs_[k * 8192 + (wc * 64 + 32 + j * 16 + r) * 32 + (q ^ sw) * 8];
        if (pf) { gl2lds16(gA + kn + soff[2], Asn + slds[2]);
                  gl2lds16(gA + kn + soff[3], Asn + slds[3]); }
        __builtin_amdgcn_sched_barrier(0);
        __builtin_amdgcn_s_barrier();
        __builtin_amdgcn_s_setprio(1);
        #pragma unroll
        for (int s = 0; s < 4; ++s)
            #pragma unroll
            for (int j = 0; j < 2; ++j)
                #pragma unroll
                for (int k = 0; k < 2; ++k)
                    acc[s][2 + j] = __builtin_amdgcn_mfma_f32_16x16x32_bf16(av[s][k], bv[1][j][k],
                                                                            acc[s][2 + j], 0, 0, 0);
        __builtin_amdgcn_s_setprio(0);
        __builtin_amdgcn_s_barrier();

        // ---- P3: read av(h=1); stage B issues 0,1 ----
        #pragma unroll
        for (int s = 0; s < 4; ++s)
            #pragma unroll
            for (int k = 0; k < 2; ++k)
                av[s][k] = *(const short8*)&As_[k * 8192 + (wr * 128 + 64 + s * 16 + r) * 32 + (q ^ sw) * 8];
        if (pf) { gl2lds16(gB + kn + soff[0], Bsn + slds[0]);
                  gl2lds16(gB + kn + soff[1], Bsn + slds[1]); }
        __builtin_amdgcn_sched_barrier(0);
        __builtin_amdgcn_s_barrier();
        __builtin_amdgcn_s_setprio(1);
        #pragma unroll
        for (int s = 0; s < 4; ++s)
            #pragma unroll
            for (int j = 0; j < 2; ++j)
                #pragma unroll
                for (int k = 0; k < 2; ++k)
                    acc[4 + s][j] = __builtin_amdgcn_mfma_f32_16x16x32_bf16(av[s][k], bv[0][j][k],
                                                                            acc[4 + s][j], 0, 0, 0);
        __builtin_amdgcn_s_setprio(0);
        __builtin_amdgcn_s_barrier();

        // ---- P4: no reads; stage B issues 2,3; tile-boundary drain ----
        if (pf) { gl2lds16(gB + kn + soff[2], Bsn + slds[2]);
                  gl2lds16(gB + kn + soff[3], Bsn + slds[3]); }
        __builtin_amdgcn_sched_barrier(0);
        __builtin_amdgcn_s_barrier();
        __builtin_amdgcn_s_setprio(1);
        #pragma unroll
        for (int s = 0; s < 4; ++s)
            #pragma unroll
            for (int j = 0; j < 2; ++j)
                #pragma unroll
                for (int k = 0; k < 2; ++k)
                    acc[4 + s][2 + j] = __builtin_amdgcn_mfma_f32_16x16x32_bf16(av[s][k], bv[1][j][k],
                                                                                acc[4 + s][2 + j], 0, 0, 0);
        __builtin_amdgcn_s_setprio(0);
        asm volatile("s_waitcnt vmcnt(0)" ::: "memory");   // next-tile staging complete
        __builtin_amdgcn_s_barrier();
    }

    // epilogue: exp + masked sums, 16-lane reduce, one partial per (row, 64-col panel)
    int lc[4];
    #pragma unroll
    for (int cf = 0; cf < 4; ++cf) lc[cf] = labels[n0 + wc * 64 + cf * 16 + r];
    int cb = blockIdx.x * 4 + wc;
    #pragma unroll
    for (int st = 0; st < 8; ++st) {
        int labr[4]; float tr[4];
        #pragma unroll
        for (int g = 0; g < 4; ++g) {
            int rw = m0 + wr * 128 + st * 16 + q * 4 + g;
            labr[g] = labels[rw];
            tr[g] = tvals[rw];
        }
        float l4[4] = {0.f, 0.f, 0.f, 0.f}, d4[4] = {0.f, 0.f, 0.f, 0.f};
        #pragma unroll
        for (int cf = 0; cf < 4; ++cf)
            #pragma unroll
            for (int g = 0; g < 4; ++g) {
                float a = acc[st][cf][g];
                float p = exp2f(fmaf(a, c1, -c1));
                l4[g] += p;
                d4[g] += ((a > tr[g]) && (lc[cf] != labr[g])) ? p : 0.f;
            }
        #pragma unroll
        for (int g = 0; g < 4; ++g) {
            float lv = l4[g], dv = d4[g];
            for (int off = 1; off < 16; off <<= 1) {
                lv += __shfl_xor(lv, off);
                dv += __shfl_xor(dv, off);
            }
            if (r == 0) {
                int rw = m0 + wr * 128 + st * 16 + q * 4 + g;
                lP[(size_t)rw * NS + cb] = lv;
                dP[(size_t)rw * NS + cb] = dv;
            }
        }
    }
}

// ---------------- merge partials + per-row losses + global sum (atomic) ----------------
__global__ void combine(const float* __restrict__ lP, const float* __restrict__ dP,
                        const float* __restrict__ tvals, const float* __restrict__ ls,
                        float* __restrict__ out) {
    int row = blockIdx.x * 256 + threadIdx.x;
    float alpha = expf(ls[0]);
    float L = 0.f, D = 0.f;
    for (int s = 0; s < NS; ++s) {
        L += lP[(size_t)row * NS + s];
        D += dP[(size_t)row * NS + s];
    }
    float tm = alpha * (tvals[row] - 1.0f);   // t - M, with M = alpha
    float clip = logf(L) - tm;
    float py = expf(tm) / L;
    float cmp = (D > 0.f) ? py / (D / L + 1e-10f) : 0.f;
    float v = clip + cmp;
    for (int off = 1; off < 64; off <<= 1) v += __shfl_xor(v, off);
    __shared__ float w4[4];
    int wave = threadIdx.x >> 6, lane = threadIdx.x & 63;
    if (lane == 0) w4[wave] = v;
    __syncthreads();
    if (threadIdx.x == 0)
        atomicAdd(out, (w4[0] + w4[1] + w4[2] + w4[3]) * (1.0f / BATCH));
}

extern "C" void kernel_launch(void* const* d_in, const int* in_sizes, int n_in,
                              void* d_out, int out_size, void* d_ws, size_t ws_size,
                              hipStream_t stream) {
    const float* images = (const float*)d_in[0];
    const float* texts  = (const float*)d_in[1];
    const int*   labels = (const int*)d_in[2];
    const float* W_img  = (const float*)d_in[3];
    const float* W_txt  = (const float*)d_in[4];
    const float* lscale = (const float*)d_in[5];
    float* out = (float*)d_out;

    char* ws = (char*)d_ws;
    unsigned short* img_bf = (unsigned short*)(ws + 0);           // 6,291,456 B
    unsigned short* txt_bf = (unsigned short*)(ws + 6291456);     // 6,291,456 B
    unsigned short* wt_img = (unsigned short*)(ws + 12582912);    //   786,432 B
    unsigned short* wt_txt = (unsigned short*)(ws + 13369344);    //   786,432 B
    unsigned short* proj_i = (unsigned short*)(ws + 14155776);    // 4,194,304 B (bf16 img_n)
    unsigned short* proj_t = (unsigned short*)(ws + 18350080);    // 4,194,304 B (bf16 txt_n)
    // aliased over dead img_bf region (written only after the fused gemm):
    float*          lP     = (float*)(ws + 0);                    // 1,048,576 B [4096][NS]
    float*          dP     = (float*)(ws + 1048576);              // 1,048,576 B
    float*          tvals  = (float*)(ws + 2097152);              //    16,384 B

    hipMemsetAsync(out, 0, sizeof(float), stream);
    prep<<<6912, 256, 0, stream>>>(images, texts, W_img, W_txt, img_bf, txt_bf, wt_img, wt_txt);
    gemm_nt<<<dim3(BATCH / 128, EDIM / 64, 2), 256, 0, stream>>>(img_bf, txt_bf, wt_img, wt_txt,
                                                                 proj_i, proj_t);
    norm_rows<<<dim3(BATCH / 4, 2), 256, 0, stream>>>(proj_i, proj_t);
    tdot<<<BATCH / 4, 256, 0, stream>>>(proj_i, proj_t, labels, tvals);
    flash_pass<<<dim3(BATCH / 256, BATCH / 256), 512, 0, stream>>>(proj_i, proj_t, labels, tvals,
                                                                   lscale, lP, dP);
    combine<<<16, 256, 0, stream>>>(lP, dP, tvals, lscale, out);
}

// Round 5
// 134.635 us; speedup vs baseline: 1.1722x; 1.0362x over previous
//
#include <hip/hip_runtime.h>
#include <stdint.h>

#define BATCH 4096
#define DDIM  768
#define EDIM  512
#define NSPLIT 16
#define LOG2E 1.44269504088896340736f

using short8  = __attribute__((ext_vector_type(8))) short;
using float4v = __attribute__((ext_vector_type(4))) float;

__device__ __forceinline__ unsigned short f2bf(float x) {
    union { float f; uint32_t u; } v; v.f = x;
    uint32_t u = v.u;
    u += 0x7FFFu + ((u >> 16) & 1u);   // round-to-nearest-even
    return (unsigned short)(u >> 16);
}
__device__ __forceinline__ float bf2f(unsigned short h) {
    union { uint32_t u; float f; } v; v.u = ((uint32_t)h) << 16;
    return v.f;
}

// pack 8 f32 -> 8 bf16 (RNE) via v_cvt_pk_bf16_f32 (no builtin on gfx950; T12 recipe)
__device__ __forceinline__ short8 cvt8(float4 v0, float4 v1) {
    union { short8 s8; uint32_t w[4]; } u;
    asm("v_cvt_pk_bf16_f32 %0, %1, %2" : "=v"(u.w[0]) : "v"(v0.x), "v"(v0.y));
    asm("v_cvt_pk_bf16_f32 %0, %1, %2" : "=v"(u.w[1]) : "v"(v0.z), "v"(v0.w));
    asm("v_cvt_pk_bf16_f32 %0, %1, %2" : "=v"(u.w[2]) : "v"(v1.x), "v"(v1.y));
    asm("v_cvt_pk_bf16_f32 %0, %1, %2" : "=v"(u.w[3]) : "v"(v1.z), "v"(v1.w));
    return u.s8;
}

// async global->LDS, 16B per lane; LDS dst must be wave-uniform base + lane*16
__device__ __forceinline__ void gl2lds16(const void* g, void* l) {
    __builtin_amdgcn_global_load_lds(
        (const __attribute__((address_space(1))) void*)g,
        (__attribute__((address_space(3))) void*)l, 16, 0, 0);
}

// ---------------- both W (K x N fp32) -> Wt (N x K bf16) in one launch ----------------
__global__ void transpose2(const float* __restrict__ Wa, const float* __restrict__ Wb,
                           unsigned short* __restrict__ Ta, unsigned short* __restrict__ Tb) {
    const float* W = blockIdx.z ? Wb : Wa;
    unsigned short* Wt = blockIdx.z ? Tb : Ta;
    __shared__ float tile[32][33];
    int n0 = blockIdx.x * 32, k0 = blockIdx.y * 32;
    int tid = threadIdx.x;
    for (int p = 0; p < 4; ++p) {
        int e = tid + p * 256; int lr = e >> 5, lc = e & 31;
        tile[lc][lr] = W[(size_t)(k0 + lr) * EDIM + n0 + lc];
    }
    __syncthreads();
    for (int p = 0; p < 4; ++p) {
        int e = tid + p * 256; int lr = e >> 5, lc = e & 31;
        Wt[(size_t)(n0 + lr) * DDIM + k0 + lc] = f2bf(tile[lr][lc]);
    }
}

// ---------------- fused NT GEMM (both modalities): Cbf16[4096x512] = A_fp32 @ W^T ----------------
// v6: A is read DIRECTLY as fp32 (no separate cvt pass): fp32 tiles staged via
// global_load_lds (16B granules, granule-XOR swizzle p_src = p ^ (row&7)), converted to
// bf16 in-register with v_cvt_pk_bf16_f32 when building MFMA fragments (4 instr/frag).
// Saves the 12 MB bf16 intermediate write + 12 MB re-read of the old cvt2 pass.
// grid (32, 8, 2); block 256 = 4 waves; tile 128x64, wave = 32 rows x 64 cols.
// LDS: A 2x32 KB fp32 + B 2x8 KB bf16 = 80 KB -> 2 blocks/CU (grid is 2/CU anyway).
__global__ __launch_bounds__(256) void gemm_nt(const float* __restrict__ Aimg,
                                               const float* __restrict__ Atxt,
                                               const unsigned short* __restrict__ Bimg,
                                               const unsigned short* __restrict__ Btxt,
                                               unsigned short* __restrict__ Cimg,
                                               unsigned short* __restrict__ Ctxt) {
    const float* A           = blockIdx.z ? Atxt : Aimg;
    const unsigned short* Bm = blockIdx.z ? Btxt : Bimg;
    unsigned short* C        = blockIdx.z ? Ctxt : Cimg;
    __shared__ __align__(16) float As[2][128 * 64];           // 2 x 32 KB fp32
    __shared__ __align__(16) unsigned short Bs[2][64 * 64];   // 2 x  8 KB bf16
    int tid = threadIdx.x;
    int wave = tid >> 6, lane = tid & 63;
    int q = lane >> 4, r = lane & 15;
    int m0 = blockIdx.x * 128, n0 = blockIdx.y * 64;
    int sw = (r >> 1) & 3;

    // A staging: 128 rows x 64 k fp32 = 32 KB = 8 issues x 256 thr x 16B.
    // LDS pos p (row = p>>4, granule slot kqp = p&15) holds global granule kq = kqp ^ (row&7)
    // (pre-swizzled SOURCE + swizzled READ; LDS dst stays linear per gl2lds rules).
    const float* gsA[8];
    float* lsA[8];
    for (int i = 0; i < 8; ++i) {
        int p = i * 256 + tid;
        int row = p >> 4, kqp = p & 15;
        int kq = kqp ^ (row & 7);
        gsA[i] = &A[(size_t)(m0 + row) * DDIM + kq * 4];
        lsA[i] = &As[0][p * 4];
    }
    // B staging: unchanged bf16 path (R2-verified swizzle)
    const unsigned short* gsB[2];
    unsigned short* lsB[2];
    for (int i = 0; i < 2; ++i) {
        int u = i * 256 + tid;
        int kc2 = u >> 8, row = (u >> 2) & 63, kq = u & 3;
        int kq2 = kq ^ ((row >> 1) & 3);
        gsB[i] = &Bm[(size_t)(n0 + row) * DDIM + kc2 * 32 + kq2 * 8];
        lsB[i] = &Bs[0][u * 8];
    }

    float4v acc[2][4];
    for (int a = 0; a < 2; ++a)
        for (int t = 0; t < 4; ++t) acc[a][t] = (float4v){0.f, 0.f, 0.f, 0.f};

    for (int i = 0; i < 8; ++i) gl2lds16(gsA[i], lsA[i]);
    for (int i = 0; i < 2; ++i) gl2lds16(gsB[i], lsB[i]);
    __syncthreads();

    for (int it = 0; it < DDIM / 64; ++it) {
        int b = it & 1;
        if (it < DDIM / 64 - 1) {
            int k0 = (it + 1) * 64;
            for (int i = 0; i < 8; ++i) gl2lds16(gsA[i] + k0, lsA[i] + (b ^ 1) * (128 * 64));
            for (int i = 0; i < 2; ++i) gl2lds16(gsB[i] + k0, lsB[i] + (b ^ 1) * (64 * 64));
        }
        #pragma unroll
        for (int kc2 = 0; kc2 < 2; ++kc2) {
            int R0r = wave * 32 + r;
            int g0 = kc2 * 8 + (q ^ sw) * 2;           // 16B-granule index (even)
            int e = R0r & 7;                            // same for R0r and R0r+16
            int p0 = g0 ^ e, p1 = (g0 + 1) ^ e;
            float4 v0 = *(const float4*)&As[b][R0r * 64 + p0 * 4];
            float4 v1 = *(const float4*)&As[b][R0r * 64 + p1 * 4];
            float4 w0 = *(const float4*)&As[b][(R0r + 16) * 64 + p0 * 4];
            float4 w1 = *(const float4*)&As[b][(R0r + 16) * 64 + p1 * 4];
            short8 a0 = cvt8(v0, v1);
            short8 a1 = cvt8(w0, w1);
            #pragma unroll
            for (int t = 0; t < 4; ++t) {
                short8 bfr = *(const short8*)&Bs[b][kc2 * 2048 + (t * 16 + r) * 32 + (q ^ sw) * 8];
                acc[0][t] = __builtin_amdgcn_mfma_f32_16x16x32_bf16(a0, bfr, acc[0][t], 0, 0, 0);
                acc[1][t] = __builtin_amdgcn_mfma_f32_16x16x32_bf16(a1, bfr, acc[1][t], 0, 0, 0);
            }
        }
        __syncthreads();   // drains prefetch vmcnt + guards buffer reuse
    }
    for (int rg = 0; rg < 2; ++rg)
        for (int t = 0; t < 4; ++t)
            for (int g = 0; g < 4; ++g)
                C[(size_t)(m0 + wave * 32 + rg * 16 + q * 4 + g) * EDIM + n0 + t * 16 + r] =
                    f2bf(acc[rg][t][g]);
}

// ---------------- fused: inverse row norms (both) + tvals, one pass, no in-place writes ----------
// wave per row: rn_img[i] = 1/||img_p[i]||, rn_txt[i] = 1/||txt_p[i]||,
// tvals[i] = dot(img_p[i], txt_p[lab]) * rn_img[i] * (1/||txt_p[lab]||)  (all from RAW proj)
__global__ void rnorm(const unsigned short* __restrict__ pi, const unsigned short* __restrict__ pt,
                      const int* __restrict__ labels,
                      float* __restrict__ rn_i, float* __restrict__ rn_t,
                      float* __restrict__ tout) {
    int wave = threadIdx.x >> 6, lane = threadIdx.x & 63;
    int row = blockIdx.x * 4 + wave;
    int lab = labels[row];
    union { unsigned short us[8]; uint4 u4; } a, b, c;
    a.u4 = *(const uint4*)&pi[(size_t)row * 512 + lane * 8];
    b.u4 = *(const uint4*)&pt[(size_t)row * 512 + lane * 8];
    c.u4 = *(const uint4*)&pt[(size_t)lab * 512 + lane * 8];
    float si = 0.f, st = 0.f, sl = 0.f, dt = 0.f;
    #pragma unroll
    for (int j = 0; j < 8; ++j) {
        float fa = bf2f(a.us[j]), fb = bf2f(b.us[j]), fc = bf2f(c.us[j]);
        si += fa * fa; st += fb * fb; sl += fc * fc; dt += fa * fc;
    }
    for (int off = 1; off < 64; off <<= 1) {
        si += __shfl_xor(si, off);
        st += __shfl_xor(st, off);
        sl += __shfl_xor(sl, off);
        dt += __shfl_xor(dt, off);
    }
    if (lane == 0) {
        float ri = rsqrtf(si);
        rn_i[row] = ri;
        rn_t[row] = rsqrtf(st);
        tout[row] = dt * ri * rsqrtf(sl);
    }
}

// ---------------- fused logits + fixed-max softmax sums + masked denom ----------------
// v6 = R0's v1 structure EXACTLY (best measured across R0-R4), on RAW projections:
// cosines recovered in the fold via a = acc * rn_img[row] * rn_txt[col].
// grid (64, 16); block 256 = 4 waves; wave: 16 rows x 256 cols (split)
// Fixed max M = alpha (|cos| <= 1) -> per-lane accumulation only, fold once per 64-col tile.
// NOTE: no min-waves in launch_bounds — (256,4)/(256,2) cap VGPR and spill af[16].
__global__ __launch_bounds__(256) void flash_pass(
    const unsigned short* __restrict__ img, const unsigned short* __restrict__ txt,
    const int* __restrict__ labels, const float* __restrict__ tvals,
    const float* __restrict__ rn_i, const float* __restrict__ rn_t,
    const float* __restrict__ ls,
    float* __restrict__ lP, float* __restrict__ dP) {
    __shared__ __align__(16) unsigned short Bs[8 * 64 * 32];  // 32 KB
    int tid = threadIdx.x;
    int wave = tid >> 6, lane = tid & 63;
    int q = lane >> 4, r = lane & 15;
    int row0 = blockIdx.x * 64 + wave * 16;
    int split = blockIdx.y;
    float alpha = expf(ls[0]);
    float c1 = alpha * LOG2E;          // p = exp2(c1*(cos - 1)) = e^{s - M}

    int srow = tid >> 2, skp = tid & 3;
    int skp2 = skp ^ ((srow >> 1) & 3);
    int sw = (r >> 1) & 3;

    // A fragments (16 rows x K=512) register-resident: 64 VGPRs
    short8 af[16];
    for (int kc = 0; kc < 16; ++kc)
        af[kc] = *(const short8*)&img[(size_t)(row0 + r) * 512 + kc * 32 + q * 8];

    int labr[4]; float tr[4], rnr[4];
    for (int g = 0; g < 4; ++g) {
        int rw = row0 + q * 4 + g;
        labr[g] = labels[rw];
        tr[g] = tvals[rw];
        rnr[g] = rn_i[rw];
    }
    float l[4] = {0.f, 0.f, 0.f, 0.f}, d[4] = {0.f, 0.f, 0.f, 0.f};

    for (int ct = 0; ct < 4; ++ct) {
        int colbase = split * 256 + ct * 64;
        const unsigned short* gB = &txt[(size_t)(colbase + srow) * 512 + skp2 * 8];
        float4v acc[4];
        for (int t = 0; t < 4; ++t) acc[t] = (float4v){0.f, 0.f, 0.f, 0.f};
        for (int h = 0; h < 2; ++h) {
            __syncthreads();
            for (int i = 0; i < 8; ++i)
                gl2lds16(gB + h * 256 + i * 32, &Bs[i * 2048 + tid * 8]);
            __syncthreads();
            for (int kc = 0; kc < 8; ++kc) {
                short8 a = af[h * 8 + kc];
                for (int t = 0; t < 4; ++t) {
                    short8 bf = *(const short8*)&Bs[(kc * 64 + t * 16 + r) * 32 + (q ^ sw) * 8];
                    acc[t] = __builtin_amdgcn_mfma_f32_16x16x32_bf16(a, bf, acc[t], 0, 0, 0);
                }
            }
        }
        for (int t = 0; t < 4; ++t) {
            int cix = colbase + t * 16 + r;
            int lc = labels[cix];
            float rc = rn_t[cix];
            for (int g = 0; g < 4; ++g) {
                float a = acc[t][g] * (rc * rnr[g]);   // cosine
                float p = exp2f(fmaf(a, c1, -c1));
                l[g] += p;
                d[g] += ((a > tr[g]) && (lc != labr[g])) ? p : 0.f;
            }
        }
    }
    for (int g = 0; g < 4; ++g) {
        float lv = l[g], dv = d[g];
        for (int off = 1; off < 16; off <<= 1) {
            lv += __shfl_xor(lv, off);
            dv += __shfl_xor(dv, off);
        }
        if (r == 0) {
            int rw = row0 + q * 4 + g;
            lP[(size_t)rw * NSPLIT + split] = lv;
            dP[(size_t)rw * NSPLIT + split] = dv;
        }
    }
}

// ---------------- merge splits + per-row losses + global sum (atomic) ----------------
__global__ void combine(const float* __restrict__ lP, const float* __restrict__ dP,
                        const float* __restrict__ tvals, const float* __restrict__ ls,
                        float* __restrict__ out) {
    int row = blockIdx.x * 256 + threadIdx.x;
    float alpha = expf(ls[0]);
    float L = 0.f, D = 0.f;
    for (int s = 0; s < NSPLIT; ++s) {
        L += lP[(size_t)row * NSPLIT + s];
        D += dP[(size_t)row * NSPLIT + s];
    }
    float tm = alpha * (tvals[row] - 1.0f);   // t - M, with M = alpha
    float clip = logf(L) - tm;
    float py = expf(tm) / L;
    float cmp = (D > 0.f) ? py / (D / L + 1e-10f) : 0.f;
    float v = clip + cmp;
    for (int off = 1; off < 64; off <<= 1) v += __shfl_xor(v, off);
    __shared__ float w4[4];
    int wave = threadIdx.x >> 6, lane = threadIdx.x & 63;
    if (lane == 0) w4[wave] = v;
    __syncthreads();
    if (threadIdx.x == 0)
        atomicAdd(out, (w4[0] + w4[1] + w4[2] + w4[3]) * (1.0f / BATCH));
}

extern "C" void kernel_launch(void* const* d_in, const int* in_sizes, int n_in,
                              void* d_out, int out_size, void* d_ws, size_t ws_size,
                              hipStream_t stream) {
    const float* images = (const float*)d_in[0];
    const float* texts  = (const float*)d_in[1];
    const int*   labels = (const int*)d_in[2];
    const float* W_img  = (const float*)d_in[3];
    const float* W_txt  = (const float*)d_in[4];
    const float* lscale = (const float*)d_in[5];
    float* out = (float*)d_out;

    char* ws = (char*)d_ws;
    unsigned short* wt_img = (unsigned short*)(ws + 0);           //   786,432 B
    unsigned short* wt_txt = (unsigned short*)(ws + 786432);      //   786,432 B
    unsigned short* proj_i = (unsigned short*)(ws + 1572864);     // 4,194,304 B (bf16 raw img proj)
    unsigned short* proj_t = (unsigned short*)(ws + 5767168);     // 4,194,304 B (bf16 raw txt proj)
    float*          rn_img = (float*)(ws + 9961472);              //    16,384 B
    float*          rn_txt = (float*)(ws + 9977856);              //    16,384 B
    float*          tvals  = (float*)(ws + 9994240);              //    16,384 B
    float*          lP     = (float*)(ws + 10010624);             //   262,144 B
    float*          dP     = (float*)(ws + 10272768);             //   262,144 B

    hipMemsetAsync(out, 0, sizeof(float), stream);
    transpose2<<<dim3(EDIM / 32, DDIM / 32, 2), 256, 0, stream>>>(W_img, W_txt, wt_img, wt_txt);
    gemm_nt<<<dim3(BATCH / 128, EDIM / 64, 2), 256, 0, stream>>>(images, texts, wt_img, wt_txt,
                                                                 proj_i, proj_t);
    rnorm<<<BATCH / 4, 256, 0, stream>>>(proj_i, proj_t, labels, rn_img, rn_txt, tvals);
    flash_pass<<<dim3(BATCH / 64, NSPLIT), 256, 0, stream>>>(proj_i, proj_t, labels, tvals,
                                                             rn_img, rn_txt, lscale, lP, dP);
    combine<<<16, 256, 0, stream>>>(lP, dP, tvals, lscale, out);
}

// Round 6
// 133.724 us; speedup vs baseline: 1.1802x; 1.0068x over previous
//
#include <hip/hip_runtime.h>
#include <stdint.h>

#define BATCH 4096
#define DDIM  768
#define EDIM  512
#define NSPLIT 16
#define LOG2E 1.44269504088896340736f

using short8  = __attribute__((ext_vector_type(8))) short;
using float4v = __attribute__((ext_vector_type(4))) float;

__device__ __forceinline__ unsigned short f2bf(float x) {
    union { float f; uint32_t u; } v; v.f = x;
    uint32_t u = v.u;
    u += 0x7FFFu + ((u >> 16) & 1u);   // round-to-nearest-even
    return (unsigned short)(u >> 16);
}
__device__ __forceinline__ float bf2f(unsigned short h) {
    union { uint32_t u; float f; } v; v.u = ((uint32_t)h) << 16;
    return v.f;
}

// pack 8 f32 -> 8 bf16 (RNE) via v_cvt_pk_bf16_f32 (no builtin on gfx950; T12 recipe)
__device__ __forceinline__ short8 cvt8(float4 v0, float4 v1) {
    union { short8 s8; uint32_t w[4]; } u;
    asm("v_cvt_pk_bf16_f32 %0, %1, %2" : "=v"(u.w[0]) : "v"(v0.x), "v"(v0.y));
    asm("v_cvt_pk_bf16_f32 %0, %1, %2" : "=v"(u.w[1]) : "v"(v0.z), "v"(v0.w));
    asm("v_cvt_pk_bf16_f32 %0, %1, %2" : "=v"(u.w[2]) : "v"(v1.x), "v"(v1.y));
    asm("v_cvt_pk_bf16_f32 %0, %1, %2" : "=v"(u.w[3]) : "v"(v1.z), "v"(v1.w));
    return u.s8;
}

// async global->LDS, 16B per lane; LDS dst must be wave-uniform base + lane*16
__device__ __forceinline__ void gl2lds16(const void* g, void* l) {
    __builtin_amdgcn_global_load_lds(
        (const __attribute__((address_space(1))) void*)g,
        (__attribute__((address_space(3))) void*)l, 16, 0, 0);
}

// ---------------- both W (K x N fp32) -> Wt (N x K bf16) in one launch ----------------
__global__ void transpose2(const float* __restrict__ Wa, const float* __restrict__ Wb,
                           unsigned short* __restrict__ Ta, unsigned short* __restrict__ Tb) {
    const float* W = blockIdx.z ? Wb : Wa;
    unsigned short* Wt = blockIdx.z ? Tb : Ta;
    __shared__ float tile[32][33];
    int n0 = blockIdx.x * 32, k0 = blockIdx.y * 32;
    int tid = threadIdx.x;
    for (int p = 0; p < 4; ++p) {
        int e = tid + p * 256; int lr = e >> 5, lc = e & 31;
        tile[lc][lr] = W[(size_t)(k0 + lr) * EDIM + n0 + lc];
    }
    __syncthreads();
    for (int p = 0; p < 4; ++p) {
        int e = tid + p * 256; int lr = e >> 5, lc = e & 31;
        Wt[(size_t)(n0 + lr) * DDIM + k0 + lc] = f2bf(tile[lr][lc]);
    }
}

// ---------------- fused NT GEMM (both modalities): Cbf16[4096x512] = A_fp32 @ W^T ----------------
// A read DIRECTLY as fp32 (no cvt pass): staged via global_load_lds (16B granules,
// granule-XOR swizzle p_src = p ^ (row&7)), converted to bf16 in-register with
// v_cvt_pk_bf16_f32 when building MFMA fragments.
// grid (32, 8, 2); block 256 = 4 waves; tile 128x64, wave = 32 rows x 64 cols.
// LDS: A 2x32 KB fp32 + B 2x8 KB bf16 = 80 KB.
__global__ __launch_bounds__(256) void gemm_nt(const float* __restrict__ Aimg,
                                               const float* __restrict__ Atxt,
                                               const unsigned short* __restrict__ Bimg,
                                               const unsigned short* __restrict__ Btxt,
                                               unsigned short* __restrict__ Cimg,
                                               unsigned short* __restrict__ Ctxt) {
    const float* A           = blockIdx.z ? Atxt : Aimg;
    const unsigned short* Bm = blockIdx.z ? Btxt : Bimg;
    unsigned short* C        = blockIdx.z ? Ctxt : Cimg;
    __shared__ __align__(16) float As[2][128 * 64];           // 2 x 32 KB fp32
    __shared__ __align__(16) unsigned short Bs[2][64 * 64];   // 2 x  8 KB bf16
    int tid = threadIdx.x;
    int wave = tid >> 6, lane = tid & 63;
    int q = lane >> 4, r = lane & 15;
    int m0 = blockIdx.x * 128, n0 = blockIdx.y * 64;
    int sw = (r >> 1) & 3;

    const float* gsA[8];
    float* lsA[8];
    for (int i = 0; i < 8; ++i) {
        int p = i * 256 + tid;
        int row = p >> 4, kqp = p & 15;
        int kq = kqp ^ (row & 7);
        gsA[i] = &A[(size_t)(m0 + row) * DDIM + kq * 4];
        lsA[i] = &As[0][p * 4];
    }
    const unsigned short* gsB[2];
    unsigned short* lsB[2];
    for (int i = 0; i < 2; ++i) {
        int u = i * 256 + tid;
        int kc2 = u >> 8, row = (u >> 2) & 63, kq = u & 3;
        int kq2 = kq ^ ((row >> 1) & 3);
        gsB[i] = &Bm[(size_t)(n0 + row) * DDIM + kc2 * 32 + kq2 * 8];
        lsB[i] = &Bs[0][u * 8];
    }

    float4v acc[2][4];
    for (int a = 0; a < 2; ++a)
        for (int t = 0; t < 4; ++t) acc[a][t] = (float4v){0.f, 0.f, 0.f, 0.f};

    for (int i = 0; i < 8; ++i) gl2lds16(gsA[i], lsA[i]);
    for (int i = 0; i < 2; ++i) gl2lds16(gsB[i], lsB[i]);
    __syncthreads();

    for (int it = 0; it < DDIM / 64; ++it) {
        int b = it & 1;
        if (it < DDIM / 64 - 1) {
            int k0 = (it + 1) * 64;
            for (int i = 0; i < 8; ++i) gl2lds16(gsA[i] + k0, lsA[i] + (b ^ 1) * (128 * 64));
            for (int i = 0; i < 2; ++i) gl2lds16(gsB[i] + k0, lsB[i] + (b ^ 1) * (64 * 64));
        }
        #pragma unroll
        for (int kc2 = 0; kc2 < 2; ++kc2) {
            int R0r = wave * 32 + r;
            int g0 = kc2 * 8 + (q ^ sw) * 2;           // 16B-granule index (even)
            int e = R0r & 7;                            // same for R0r and R0r+16
            int p0 = g0 ^ e, p1 = (g0 + 1) ^ e;
            float4 v0 = *(const float4*)&As[b][R0r * 64 + p0 * 4];
            float4 v1 = *(const float4*)&As[b][R0r * 64 + p1 * 4];
            float4 w0 = *(const float4*)&As[b][(R0r + 16) * 64 + p0 * 4];
            float4 w1 = *(const float4*)&As[b][(R0r + 16) * 64 + p1 * 4];
            short8 a0 = cvt8(v0, v1);
            short8 a1 = cvt8(w0, w1);
            #pragma unroll
            for (int t = 0; t < 4; ++t) {
                short8 bfr = *(const short8*)&Bs[b][kc2 * 2048 + (t * 16 + r) * 32 + (q ^ sw) * 8];
                acc[0][t] = __builtin_amdgcn_mfma_f32_16x16x32_bf16(a0, bfr, acc[0][t], 0, 0, 0);
                acc[1][t] = __builtin_amdgcn_mfma_f32_16x16x32_bf16(a1, bfr, acc[1][t], 0, 0, 0);
            }
        }
        __syncthreads();   // drains prefetch vmcnt + guards buffer reuse
    }
    for (int rg = 0; rg < 2; ++rg)
        for (int t = 0; t < 4; ++t)
            for (int g = 0; g < 4; ++g)
                C[(size_t)(m0 + wave * 32 + rg * 16 + q * 4 + g) * EDIM + n0 + t * 16 + r] =
                    f2bf(acc[rg][t][g]);
}

// ---------------- fused: inverse row norms (both) + tvals, one pass ----------------
__global__ void rnorm(const unsigned short* __restrict__ pi, const unsigned short* __restrict__ pt,
                      const int* __restrict__ labels,
                      float* __restrict__ rn_i, float* __restrict__ rn_t,
                      float* __restrict__ tout) {
    int wave = threadIdx.x >> 6, lane = threadIdx.x & 63;
    int row = blockIdx.x * 4 + wave;
    int lab = labels[row];
    union { unsigned short us[8]; uint4 u4; } a, b, c;
    a.u4 = *(const uint4*)&pi[(size_t)row * 512 + lane * 8];
    b.u4 = *(const uint4*)&pt[(size_t)row * 512 + lane * 8];
    c.u4 = *(const uint4*)&pt[(size_t)lab * 512 + lane * 8];
    float si = 0.f, st = 0.f, sl = 0.f, dt = 0.f;
    #pragma unroll
    for (int j = 0; j < 8; ++j) {
        float fa = bf2f(a.us[j]), fb = bf2f(b.us[j]), fc = bf2f(c.us[j]);
        si += fa * fa; st += fb * fb; sl += fc * fc; dt += fa * fc;
    }
    for (int off = 1; off < 64; off <<= 1) {
        si += __shfl_xor(si, off);
        st += __shfl_xor(st, off);
        sl += __shfl_xor(sl, off);
        dt += __shfl_xor(dt, off);
    }
    if (lane == 0) {
        float ri = rsqrtf(si);
        rn_i[row] = ri;
        rn_t[row] = rsqrtf(st);
        tout[row] = dt * ri * rsqrtf(sl);
    }
}

// ---------------- fused logits + fixed-max softmax sums + masked denom ----------------
// v7 = R5's proven math/geometry with THREE isolated scheduling changes:
//  (1) 16 half-size stages (32 cols x 256 k = 16 KB), double-buffered 2x16 KB
//      -> LDS stays 32 KB (occupancy unchanged vs R5; R1's 64 KB dbuf halved it).
//  (2) prefetch next stage ISSUED BEFORE the MFMA loop; ONE barrier per phase
//      (same 16 barriers as R5, but each vmcnt drain hides under 16 MFMA + fold).
//  (3) grid (NSPLIT, 64): XCD = split&7 -> 2 splits/XCD -> txt slice 512 KB, L2-resident.
// Fixed max M = alpha (|cos| <= 1); cosines recovered via acc * rn_i[row] * rn_t[col].
// NOTE: no min-waves in launch_bounds (R2: (256,2) caps VGPR at 128 and spills af).
__global__ __launch_bounds__(256) void flash_pass(
    const unsigned short* __restrict__ img, const unsigned short* __restrict__ txt,
    const int* __restrict__ labels, const float* __restrict__ tvals,
    const float* __restrict__ rn_i, const float* __restrict__ rn_t,
    const float* __restrict__ ls,
    float* __restrict__ lP, float* __restrict__ dP) {
    __shared__ __align__(16) unsigned short Bs[2][8192];  // 2 x 16 KB
    int tid = threadIdx.x;
    int wave = tid >> 6, lane = tid & 63;
    int q = lane >> 4, r = lane & 15;
    int split = blockIdx.x;                 // fast dim -> XCD = split & 7
    int row0 = blockIdx.y * 64 + wave * 16;
    float alpha = expf(ls[0]);
    float c1 = alpha * LOG2E;               // p = exp2(c1*(cos - 1)) = e^{s - M}

    // staging coords: stage = 32 cols x 256 k bf16 = 16 KB = 4 issues x 256 thr x 16B
    // granule u = i*256+tid: kc = u>>7 (32-k chunk), col = (tid>>2)&31, kq = tid&3
    int scol = (tid >> 2) & 31, skp = tid & 3;
    int skp2 = skp ^ ((scol >> 1) & 3);     // same XOR family as all verified kernels
    int sw = (r >> 1) & 3;

    const unsigned short* gsB[4];
    int lsB[4];
    for (int i = 0; i < 4; ++i) {
        int u = i * 256 + tid;
        int kc = u >> 7;
        gsB[i] = &txt[(size_t)(split * 256 + scol) * 512 + kc * 32 + skp2 * 8];
        lsB[i] = u * 8;                     // ushort offset; +buf*8192 at use
    }

    // phase sn (0..15): ct2 = sn>>1 (32-col tile), h = sn&1 (256-k half)
    // global advance for phase sn: cols += ct2*32 -> +ct2*32*512 ; k += h*256
    // issue stage 0 immediately so it flies under the af/labels loads
    for (int i = 0; i < 4; ++i) gl2lds16(gsB[i], &Bs[0][lsB[i]]);

    // A fragments (16 rows x K=512) register-resident: 64 VGPRs
    short8 af[16];
    for (int kc = 0; kc < 16; ++kc)
        af[kc] = *(const short8*)&img[(size_t)(row0 + r) * 512 + kc * 32 + q * 8];

    int labr[4]; float tr[4], rnr[4];
    for (int g = 0; g < 4; ++g) {
        int rw = row0 + q * 4 + g;
        labr[g] = labels[rw];
        tr[g] = tvals[rw];
        rnr[g] = rn_i[rw];
    }
    float l[4] = {0.f, 0.f, 0.f, 0.f}, d[4] = {0.f, 0.f, 0.f, 0.f};
    float4v acc[2];
    acc[0] = (float4v){0.f, 0.f, 0.f, 0.f};
    acc[1] = (float4v){0.f, 0.f, 0.f, 0.f};

    __syncthreads();   // stage 0 resident

    #pragma unroll
    for (int ct2 = 0; ct2 < 8; ++ct2) {
        #pragma unroll
        for (int h = 0; h < 2; ++h) {
            int s = ct2 * 2 + h;
            int buf = s & 1;
            if (s < 15) {     // prefetch stage s+1 into the other buffer BEFORE compute
                int sn = s + 1;
                int goff = (sn >> 1) * (32 * 512) + (sn & 1) * 256;
                #pragma unroll
                for (int i = 0; i < 4; ++i)
                    gl2lds16(gsB[i] + goff, &Bs[buf ^ 1][lsB[i]]);
            }
            #pragma unroll
            for (int kc = 0; kc < 8; ++kc) {
                short8 a = af[h * 8 + kc];
                #pragma unroll
                for (int t = 0; t < 2; ++t) {
                    short8 bf = *(const short8*)&Bs[buf][kc * 1024 + (t * 16 + r) * 32 + (q ^ sw) * 8];
                    acc[t] = __builtin_amdgcn_mfma_f32_16x16x32_bf16(a, bf, acc[t], 0, 0, 0);
                }
            }
            if (h == 1) {     // 32-col tile complete over full K: fold, reset acc
                int colbase = split * 256 + ct2 * 32;
                #pragma unroll
                for (int t = 0; t < 2; ++t) {
                    int cix = colbase + t * 16 + r;
                    int lc = labels[cix];
                    float rc = rn_t[cix];
                    #pragma unroll
                    for (int g = 0; g < 4; ++g) {
                        float a = acc[t][g] * (rc * rnr[g]);   // cosine
                        float p = exp2f(fmaf(a, c1, -c1));
                        l[g] += p;
                        d[g] += ((a > tr[g]) && (lc != labr[g])) ? p : 0.f;
                    }
                    acc[t] = (float4v){0.f, 0.f, 0.f, 0.f};
                }
            }
            __syncthreads();   // drains prefetch vmcnt + guards buffer reuse
        }
    }
    for (int g = 0; g < 4; ++g) {
        float lv = l[g], dv = d[g];
        for (int off = 1; off < 16; off <<= 1) {
            lv += __shfl_xor(lv, off);
            dv += __shfl_xor(dv, off);
        }
        if (r == 0) {
            int rw = row0 + q * 4 + g;
            lP[(size_t)rw * NSPLIT + split] = lv;
            dP[(size_t)rw * NSPLIT + split] = dv;
        }
    }
}

// ---------------- merge splits + per-row losses + global sum (atomic) ----------------
__global__ void combine(const float* __restrict__ lP, const float* __restrict__ dP,
                        const float* __restrict__ tvals, const float* __restrict__ ls,
                        float* __restrict__ out) {
    int row = blockIdx.x * 256 + threadIdx.x;
    float alpha = expf(ls[0]);
    float L = 0.f, D = 0.f;
    for (int s = 0; s < NSPLIT; ++s) {
        L += lP[(size_t)row * NSPLIT + s];
        D += dP[(size_t)row * NSPLIT + s];
    }
    float tm = alpha * (tvals[row] - 1.0f);   // t - M, with M = alpha
    float clip = logf(L) - tm;
    float py = expf(tm) / L;
    float cmp = (D > 0.f) ? py / (D / L + 1e-10f) : 0.f;
    float v = clip + cmp;
    for (int off = 1; off < 64; off <<= 1) v += __shfl_xor(v, off);
    __shared__ float w4[4];
    int wave = threadIdx.x >> 6, lane = threadIdx.x & 63;
    if (lane == 0) w4[wave] = v;
    __syncthreads();
    if (threadIdx.x == 0)
        atomicAdd(out, (w4[0] + w4[1] + w4[2] + w4[3]) * (1.0f / BATCH));
}

extern "C" void kernel_launch(void* const* d_in, const int* in_sizes, int n_in,
                              void* d_out, int out_size, void* d_ws, size_t ws_size,
                              hipStream_t stream) {
    const float* images = (const float*)d_in[0];
    const float* texts  = (const float*)d_in[1];
    const int*   labels = (const int*)d_in[2];
    const float* W_img  = (const float*)d_in[3];
    const float* W_txt  = (const float*)d_in[4];
    const float* lscale = (const float*)d_in[5];
    float* out = (float*)d_out;

    char* ws = (char*)d_ws;
    unsigned short* wt_img = (unsigned short*)(ws + 0);           //   786,432 B
    unsigned short* wt_txt = (unsigned short*)(ws + 786432);      //   786,432 B
    unsigned short* proj_i = (unsigned short*)(ws + 1572864);     // 4,194,304 B (bf16 raw img proj)
    unsigned short* proj_t = (unsigned short*)(ws + 5767168);     // 4,194,304 B (bf16 raw txt proj)
    float*          rn_img = (float*)(ws + 9961472);              //    16,384 B
    float*          rn_txt = (float*)(ws + 9977856);              //    16,384 B
    float*          tvals  = (float*)(ws + 9994240);              //    16,384 B
    float*          lP     = (float*)(ws + 10010624);             //   262,144 B
    float*          dP     = (float*)(ws + 10272768);             //   262,144 B

    hipMemsetAsync(out, 0, sizeof(float), stream);
    transpose2<<<dim3(EDIM / 32, DDIM / 32, 2), 256, 0, stream>>>(W_img, W_txt, wt_img, wt_txt);
    gemm_nt<<<dim3(BATCH / 128, EDIM / 64, 2), 256, 0, stream>>>(images, texts, wt_img, wt_txt,
                                                                 proj_i, proj_t);
    rnorm<<<BATCH / 4, 256, 0, stream>>>(proj_i, proj_t, labels, rn_img, rn_txt, tvals);
    flash_pass<<<dim3(NSPLIT, BATCH / 64), 256, 0, stream>>>(proj_i, proj_t, labels, tvals,
                                                             rn_img, rn_txt, lscale, lP, dP);
    combine<<<16, 256, 0, stream>>>(lP, dP, tvals, lscale, out);
}